// Round 2
// baseline (162.347 us; speedup 1.0000x reference)
//
#include <hip/hip_runtime.h>

#define B 2
#define N 16384
#define NPOINT 4096
#define C 64
#define NSAMPLE 32

// Threshold exactly as the JAX/numpy reference sees it:
// float32(double(0.1)*double(0.1)) = 0.009999999776482582f
// (NOT 0.1f*0.1f which is one ulp higher)
__device__ __forceinline__ float r2_thresh() { return (float)(0.1 * 0.1); }

// ---------------- Kernel 1: ball query, one wave (64 lanes) per query ----------------
__global__ void __launch_bounds__(256) ball_query_kernel(
    const float* __restrict__ xyz,      // (B, N, 3)
    const float* __restrict__ new_xyz,  // (B, NPOINT, 3)
    int* __restrict__ idx_out)          // (B, NPOINT, NSAMPLE)
{
    const int gtid = blockIdx.x * blockDim.x + threadIdx.x;
    const int wave = gtid >> 6;
    const int lane = threadIdx.x & 63;
    if (wave >= B * NPOINT) return;

    const int b = wave / NPOINT;
    const int j = wave - b * NPOINT;

    const float cx = new_xyz[(b * NPOINT + j) * 3 + 0];
    const float cy = new_xyz[(b * NPOINT + j) * 3 + 1];
    const float cz = new_xyz[(b * NPOINT + j) * 3 + 2];

    const float* __restrict__ xb = xyz + (size_t)b * N * 3;
    int* __restrict__ out = idx_out + ((size_t)b * NPOINT + j) * NSAMPLE;

    const float r2 = r2_thresh();

    int cnt = 0;        // wave-uniform (derived from ballot)
    int first_idx = 0;  // wave-uniform

    for (int base = 0; base < N; base += 64) {
        const int i = base + lane;
        float x = xb[i * 3 + 0];
        float y = xb[i * 3 + 1];
        float z = xb[i * 3 + 2];

        float d2;
        {
#pragma clang fp contract(off)
            float dx = x - cx;
            float dy = y - cy;
            float dz = z - cz;
            d2 = dx * dx + dy * dy + dz * dz;  // matches numpy: ((dx^2+dy^2)+dz^2), no FMA
        }
        const bool inball = d2 < r2;
        const unsigned long long mask = __ballot(inball);

        if (inball) {
            // rank of this lane among set bits below it -> preserves original point order
            const int rank = __popcll(mask & ((1ull << lane) - 1ull));
            const int pos = cnt + rank;
            if (pos < NSAMPLE) out[pos] = i;
        }
        if (cnt == 0 && mask != 0ull) {
            first_idx = base + __builtin_ctzll(mask);
        }
        cnt += __popcll(mask);
        if (cnt >= NSAMPLE) break;  // wave-uniform branch
    }

    // pad remaining slots with first in-ball index (0 if ball empty)
    if (cnt < NSAMPLE) {
        if (cnt == 0) first_idx = 0;
        for (int pos = cnt + lane; pos < NSAMPLE; pos += 64) out[pos] = first_idx;
    }
}

// ---------------- Kernel 2: grouping (gather + subtract center) ----------------
// Block = 256 threads = 8 queries x 32 samples. Grid = (NPOINT/8, B).
__global__ void __launch_bounds__(256) group_kernel(
    const float* __restrict__ xyz,      // (B, N, 3)
    const float* __restrict__ new_xyz,  // (B, NPOINT, 3)
    const float* __restrict__ feat,     // (B, C, N)
    const int* __restrict__ idx_arr,    // (B, NPOINT, NSAMPLE)
    float* __restrict__ out)            // (B, 3+C, NPOINT, NSAMPLE)
{
    const int t = threadIdx.x;
    const int s = t & 31;        // sample slot
    const int jl = t >> 5;       // 0..7 local query
    const int j = blockIdx.x * 8 + jl;
    const int b = blockIdx.y;

    const int id = idx_arr[((size_t)b * NPOINT + j) * NSAMPLE + s];

    // grouped_xyz - center
    const float px = xyz[((size_t)b * N + id) * 3 + 0] - new_xyz[((size_t)b * NPOINT + j) * 3 + 0];
    const float py = xyz[((size_t)b * N + id) * 3 + 1] - new_xyz[((size_t)b * NPOINT + j) * 3 + 1];
    const float pz = xyz[((size_t)b * N + id) * 3 + 2] - new_xyz[((size_t)b * NPOINT + j) * 3 + 2];

    const size_t plane = (size_t)NPOINT * NSAMPLE;               // 131072
    const size_t obase = (size_t)b * (3 + C) * plane + (size_t)j * NSAMPLE + s;

    out[obase + 0 * plane] = px;
    out[obase + 1 * plane] = py;
    out[obase + 2 * plane] = pz;

    const float* __restrict__ fb = feat + (size_t)b * C * N;
#pragma unroll 8
    for (int c = 0; c < C; ++c) {
        out[obase + (size_t)(3 + c) * plane] = fb[(size_t)c * N + id];
    }
}

extern "C" void kernel_launch(void* const* d_in, const int* in_sizes, int n_in,
                              void* d_out, int out_size, void* d_ws, size_t ws_size,
                              hipStream_t stream) {
    const float* xyz     = (const float*)d_in[0];  // (B, N, 3)
    const float* new_xyz = (const float*)d_in[1];  // (B, NPOINT, 3)
    const float* feat    = (const float*)d_in[2];  // (B, C, N)
    float* out = (float*)d_out;
    int* idx_ws = (int*)d_ws;  // B*NPOINT*NSAMPLE ints = 1 MB

    // Kernel 1: one wave per query; 8192 waves -> 2048 blocks of 256 (4 waves each)
    {
        const int waves = B * NPOINT;
        const int blocks = (waves * 64) / 256;
        ball_query_kernel<<<blocks, 256, 0, stream>>>(xyz, new_xyz, idx_ws);
    }
    // Kernel 2: grouping
    {
        dim3 grid(NPOINT / 8, B);
        group_kernel<<<grid, 256, 0, stream>>>(xyz, new_xyz, feat, idx_ws, out);
    }
}

// Round 3
// 118.499 us; speedup vs baseline: 1.3700x; 1.3700x over previous
//
#include <hip/hip_runtime.h>

#define B 2
#define N 16384
#define NPOINT 4096
#define C 64
#define NSAMPLE 32

// Threshold exactly as the JAX/numpy reference sees it:
// float32(double(0.1)*double(0.1)) = 0.009999999776482582f
__device__ __forceinline__ float r2_thresh() { return (float)(0.1 * 0.1); }

// ---------------- Kernel 1: ball query, one wave (64 lanes) per query ----------------
// 4x unrolled scan: 256 points per iteration, all loads issued before any use,
// so one iteration exposes one load latency instead of four.
__global__ void __launch_bounds__(256) ball_query_kernel(
    const float* __restrict__ xyz,      // (B, N, 3)
    const float* __restrict__ new_xyz,  // (B, NPOINT, 3)
    int* __restrict__ idx_out)          // (B, NPOINT, NSAMPLE)
{
    const int gtid = blockIdx.x * blockDim.x + threadIdx.x;
    const int wave = gtid >> 6;
    const int lane = threadIdx.x & 63;
    if (wave >= B * NPOINT) return;

    const int b = wave / NPOINT;
    const int j = wave - b * NPOINT;

    const float cx = new_xyz[(b * NPOINT + j) * 3 + 0];
    const float cy = new_xyz[(b * NPOINT + j) * 3 + 1];
    const float cz = new_xyz[(b * NPOINT + j) * 3 + 2];

    const float* __restrict__ xb = xyz + (size_t)b * N * 3;
    int* __restrict__ out = idx_out + ((size_t)b * NPOINT + j) * NSAMPLE;

    const float r2 = r2_thresh();
    const unsigned long long lanemask_lt = (lane == 63) ? 0x7FFFFFFFFFFFFFFFull
                                                        : ((1ull << lane) - 1ull);

    int cnt = 0;        // wave-uniform (derived from ballot)
    int first_idx = 0;  // wave-uniform

    for (int base = 0; base < N; base += 256) {
        float x[4], y[4], z[4];
#pragma unroll
        for (int u = 0; u < 4; ++u) {
            const int i = base + u * 64 + lane;
            x[u] = xb[i * 3 + 0];
            y[u] = xb[i * 3 + 1];
            z[u] = xb[i * 3 + 2];
        }

        unsigned long long m[4];
        bool inball[4];
#pragma unroll
        for (int u = 0; u < 4; ++u) {
            float d2;
            {
#pragma clang fp contract(off)
                float dx = x[u] - cx;
                float dy = y[u] - cy;
                float dz = z[u] - cz;
                d2 = dx * dx + dy * dy + dz * dz;  // matches numpy: no FMA contraction
            }
            inball[u] = d2 < r2;
            m[u] = __ballot(inball[u]);
        }

#pragma unroll
        for (int u = 0; u < 4; ++u) {
            if (inball[u]) {
                const int rank = __popcll(m[u] & lanemask_lt);
                const int pos = cnt + rank;
                if (pos < NSAMPLE) out[pos] = base + u * 64 + lane;
            }
            if (cnt == 0 && m[u] != 0ull) {
                first_idx = base + u * 64 + __builtin_ctzll(m[u]);
            }
            cnt += __popcll(m[u]);
        }
        if (cnt >= NSAMPLE) break;  // wave-uniform branch, 256-point granularity
    }

    // pad remaining slots with first in-ball index (0 if ball empty)
    if (cnt < NSAMPLE) {
        if (cnt == 0) first_idx = 0;
        for (int pos = cnt + lane; pos < NSAMPLE; pos += 64) out[pos] = first_idx;
    }
}

// ---------------- Kernel 2: grouping (gather + subtract center) ----------------
// Block = 256 threads = 8 queries x 32 samples. Grid = (NPOINT/8, B).
__global__ void __launch_bounds__(256) group_kernel(
    const float* __restrict__ xyz,      // (B, N, 3)
    const float* __restrict__ new_xyz,  // (B, NPOINT, 3)
    const float* __restrict__ feat,     // (B, C, N)
    const int* __restrict__ idx_arr,    // (B, NPOINT, NSAMPLE)
    float* __restrict__ out)            // (B, 3+C, NPOINT, NSAMPLE)
{
    const int t = threadIdx.x;
    const int s = t & 31;        // sample slot
    const int jl = t >> 5;       // 0..7 local query
    const int j = blockIdx.x * 8 + jl;
    const int b = blockIdx.y;

    const int id = idx_arr[((size_t)b * NPOINT + j) * NSAMPLE + s];

    // grouped_xyz - center
    const float px = xyz[((size_t)b * N + id) * 3 + 0] - new_xyz[((size_t)b * NPOINT + j) * 3 + 0];
    const float py = xyz[((size_t)b * N + id) * 3 + 1] - new_xyz[((size_t)b * NPOINT + j) * 3 + 1];
    const float pz = xyz[((size_t)b * N + id) * 3 + 2] - new_xyz[((size_t)b * NPOINT + j) * 3 + 2];

    const size_t plane = (size_t)NPOINT * NSAMPLE;               // 131072
    const size_t obase = (size_t)b * (3 + C) * plane + (size_t)j * NSAMPLE + s;

    out[obase + 0 * plane] = px;
    out[obase + 1 * plane] = py;
    out[obase + 2 * plane] = pz;

    const float* __restrict__ fb = feat + (size_t)b * C * N;
#pragma unroll 8
    for (int c = 0; c < C; ++c) {
        out[obase + (size_t)(3 + c) * plane] = fb[(size_t)c * N + id];
    }
}

extern "C" void kernel_launch(void* const* d_in, const int* in_sizes, int n_in,
                              void* d_out, int out_size, void* d_ws, size_t ws_size,
                              hipStream_t stream) {
    const float* xyz     = (const float*)d_in[0];  // (B, N, 3)
    const float* new_xyz = (const float*)d_in[1];  // (B, NPOINT, 3)
    const float* feat    = (const float*)d_in[2];  // (B, C, N)
    float* out = (float*)d_out;
    int* idx_ws = (int*)d_ws;  // B*NPOINT*NSAMPLE ints = 1 MB

    // Kernel 1: one wave per query; 8192 waves -> 2048 blocks of 256 (4 waves each)
    {
        const int waves = B * NPOINT;
        const int blocks = (waves * 64) / 256;
        ball_query_kernel<<<blocks, 256, 0, stream>>>(xyz, new_xyz, idx_ws);
    }
    // Kernel 2: grouping
    {
        dim3 grid(NPOINT / 8, B);
        group_kernel<<<grid, 256, 0, stream>>>(xyz, new_xyz, feat, idx_ws, out);
    }
}

// Round 5
// 77.584 us; speedup vs baseline: 2.0925x; 1.5274x over previous
//
#include <hip/hip_runtime.h>

#define B 2
#define N 16384
#define NPOINT 4096
#define C 64
#define NSAMPLE 32

// Threshold exactly as the JAX/numpy reference sees it:
// float32(double(0.1)*double(0.1)) = 0.009999999776482582f
__device__ __forceinline__ float r2_thresh() { return (float)(0.1 * 0.1); }

// ---------------- Kernel 1: ball query, one wave (64 lanes) per query ----------------
// 4x unrolled scan: 256 points per iteration, all loads issued before any use.
__global__ void __launch_bounds__(256) ball_query_kernel(
    const float* __restrict__ xyz,      // (B, N, 3)
    const float* __restrict__ new_xyz,  // (B, NPOINT, 3)
    int* __restrict__ idx_out)          // (B, NPOINT, NSAMPLE)
{
    const int gtid = blockIdx.x * blockDim.x + threadIdx.x;
    const int wave = gtid >> 6;
    const int lane = threadIdx.x & 63;
    if (wave >= B * NPOINT) return;

    const int b = wave / NPOINT;
    const int j = wave - b * NPOINT;

    const float cx = new_xyz[(b * NPOINT + j) * 3 + 0];
    const float cy = new_xyz[(b * NPOINT + j) * 3 + 1];
    const float cz = new_xyz[(b * NPOINT + j) * 3 + 2];

    const float* __restrict__ xb = xyz + (size_t)b * N * 3;
    int* __restrict__ out = idx_out + ((size_t)b * NPOINT + j) * NSAMPLE;

    const float r2 = r2_thresh();
    const unsigned long long lanemask_lt = (lane == 63) ? 0x7FFFFFFFFFFFFFFFull
                                                        : ((1ull << lane) - 1ull);

    int cnt = 0;        // wave-uniform (derived from ballot)
    int first_idx = 0;  // wave-uniform

    for (int base = 0; base < N; base += 256) {
        float x[4], y[4], z[4];
#pragma unroll
        for (int u = 0; u < 4; ++u) {
            const int i = base + u * 64 + lane;
            x[u] = xb[i * 3 + 0];
            y[u] = xb[i * 3 + 1];
            z[u] = xb[i * 3 + 2];
        }

        unsigned long long m[4];
        bool inball[4];
#pragma unroll
        for (int u = 0; u < 4; ++u) {
            float d2;
            {
#pragma clang fp contract(off)
                float dx = x[u] - cx;
                float dy = y[u] - cy;
                float dz = z[u] - cz;
                d2 = dx * dx + dy * dy + dz * dz;  // matches numpy: no FMA contraction
            }
            inball[u] = d2 < r2;
            m[u] = __ballot(inball[u]);
        }

#pragma unroll
        for (int u = 0; u < 4; ++u) {
            if (inball[u]) {
                const int rank = __popcll(m[u] & lanemask_lt);
                const int pos = cnt + rank;
                if (pos < NSAMPLE) out[pos] = base + u * 64 + lane;
            }
            if (cnt == 0 && m[u] != 0ull) {
                first_idx = base + u * 64 + __builtin_ctzll(m[u]);
            }
            cnt += __popcll(m[u]);
        }
        if (cnt >= NSAMPLE) break;  // wave-uniform, 256-point granularity
    }

    if (cnt < NSAMPLE) {
        if (cnt == 0) first_idx = 0;
        for (int pos = cnt + lane; pos < NSAMPLE; pos += 64) out[pos] = first_idx;
    }
}

// ---------------- Kernel T: transpose features (B,C,N) -> (B,N,C) ----------------
// LDS-tiled; both global read and write fully coalesced (256B per wave).
__global__ void __launch_bounds__(256) transpose_kernel(
    const float* __restrict__ feat,  // (B, C, N)
    float* __restrict__ ft)          // (B, N, C)
{
    __shared__ float tile[64 * 65];
    const int b = blockIdx.y;
    const int n0 = blockIdx.x * 64;
    const int t = threadIdx.x;
    const int l = t & 63;
    const int w = t >> 6;

#pragma unroll
    for (int it = 0; it < 16; ++it) {
        const int c = it * 4 + w;
        tile[c * 65 + l] = feat[((size_t)b * C + c) * N + n0 + l];
    }
    __syncthreads();
#pragma unroll
    for (int it = 0; it < 16; ++it) {
        const int nn = it * 4 + w;
        ft[((size_t)b * N + n0 + nn) * C + l] = tile[l * 65 + nn];
    }
}

// ---------------- Kernel 2: grouping using transposed features ----------------
// Block = 256 threads handles 2 queries x 32 samples = 64 pairs.
// Phase 1: 16 lanes per pair load the pair's 64 channels as 4 float4 (256B,
//          fully-used cache lines) into LDS. Phase 2: plane-major coalesced
//          stores (each wave stores 256B contiguous per channel).
__global__ void __launch_bounds__(256) group2_kernel(
    const float* __restrict__ xyz,      // (B, N, 3)
    const float* __restrict__ new_xyz,  // (B, NPOINT, 3)
    const float* __restrict__ ft,       // (B, N, C) transposed features
    const int* __restrict__ idx_arr,    // (B, NPOINT, NSAMPLE)
    float* __restrict__ out)            // (B, 3+C, NPOINT, NSAMPLE)
{
    __shared__ int sidx[64];
    __shared__ float sf[64 * 65];   // [pair][channel], pad 65 -> conflict-free reads

    const int t = threadIdx.x;
    const int b = blockIdx.y;
    const int j0 = blockIdx.x * 2;

    if (t < 64) sidx[t] = idx_arr[((size_t)b * NPOINT + j0) * NSAMPLE + t];
    __syncthreads();

    // Phase 1: gather features. pair p <- 16 lanes, each lane one float4.
    {
        const int lane16 = t & 15;
        const int pq = t >> 4;  // 0..15
#pragma unroll
        for (int it = 0; it < 4; ++it) {
            const int p = it * 16 + pq;
            const int id = sidx[p];
            const float4 v = *(const float4*)(ft + ((size_t)b * N + id) * C + lane16 * 4);
            float* dst = sf + p * 65 + lane16 * 4;   // 65-stride: scalar stores (not 16B-aligned)
            dst[0] = v.x; dst[1] = v.y; dst[2] = v.z; dst[3] = v.w;
        }
    }

    const size_t plane = (size_t)NPOINT * NSAMPLE;
    const size_t obase = (size_t)b * (3 + C) * plane + (size_t)j0 * NSAMPLE;

    // xyz part: pair index = t (threads 0..63)
    if (t < 64) {
        const int id = sidx[t];
        const int q = t >> 5;  // local query 0/1
        const size_t cb = ((size_t)b * NPOINT + j0 + q) * 3;
        const size_t pb = ((size_t)b * N + id) * 3;
        {
#pragma clang fp contract(off)
            out[obase + 0 * plane + t] = xyz[pb + 0] - new_xyz[cb + 0];
            out[obase + 1 * plane + t] = xyz[pb + 1] - new_xyz[cb + 1];
            out[obase + 2 * plane + t] = xyz[pb + 2] - new_xyz[cb + 2];
        }
    }
    __syncthreads();

    // Phase 2: per iteration, wave w writes channel c = it*4+w for all 64 pairs.
    const int l = t & 63;
    const int w = t >> 6;
#pragma unroll
    for (int it = 0; it < 16; ++it) {
        const int c = it * 4 + w;
        out[obase + (size_t)(3 + c) * plane + l] = sf[l * 65 + c];
    }
}

// ---------------- Fallback grouping (original, used if ws too small) ----------------
__global__ void __launch_bounds__(256) group_kernel(
    const float* __restrict__ xyz,
    const float* __restrict__ new_xyz,
    const float* __restrict__ feat,     // (B, C, N)
    const int* __restrict__ idx_arr,
    float* __restrict__ out)
{
    const int t = threadIdx.x;
    const int s = t & 31;
    const int jl = t >> 5;
    const int j = blockIdx.x * 8 + jl;
    const int b = blockIdx.y;

    const int id = idx_arr[((size_t)b * NPOINT + j) * NSAMPLE + s];

    const float px = xyz[((size_t)b * N + id) * 3 + 0] - new_xyz[((size_t)b * NPOINT + j) * 3 + 0];
    const float py = xyz[((size_t)b * N + id) * 3 + 1] - new_xyz[((size_t)b * NPOINT + j) * 3 + 1];
    const float pz = xyz[((size_t)b * N + id) * 3 + 2] - new_xyz[((size_t)b * NPOINT + j) * 3 + 2];

    const size_t plane = (size_t)NPOINT * NSAMPLE;
    const size_t obase = (size_t)b * (3 + C) * plane + (size_t)j * NSAMPLE + s;

    out[obase + 0 * plane] = px;
    out[obase + 1 * plane] = py;
    out[obase + 2 * plane] = pz;

    const float* __restrict__ fb = feat + (size_t)b * C * N;
#pragma unroll 8
    for (int c = 0; c < C; ++c) {
        out[obase + (size_t)(3 + c) * plane] = fb[(size_t)c * N + id];
    }
}

extern "C" void kernel_launch(void* const* d_in, const int* in_sizes, int n_in,
                              void* d_out, int out_size, void* d_ws, size_t ws_size,
                              hipStream_t stream) {
    const float* xyz     = (const float*)d_in[0];  // (B, N, 3)
    const float* new_xyz = (const float*)d_in[1];  // (B, NPOINT, 3)
    const float* feat    = (const float*)d_in[2];  // (B, C, N)
    float* out = (float*)d_out;

    const size_t idx_bytes = (size_t)B * NPOINT * NSAMPLE * sizeof(int);   // 1 MB
    const size_t ft_bytes  = (size_t)B * N * C * sizeof(float);            // 8.4 MB

    int* idx_ws = (int*)d_ws;
    float* ft = (float*)((char*)d_ws + idx_bytes);

    const bool use_transposed = (ws_size >= idx_bytes + ft_bytes);

    if (use_transposed) {
        dim3 tg(N / 64, B);
        transpose_kernel<<<tg, 256, 0, stream>>>(feat, ft);
    }

    {
        const int waves = B * NPOINT;
        const int blocks = (waves * 64) / 256;
        ball_query_kernel<<<blocks, 256, 0, stream>>>(xyz, new_xyz, idx_ws);
    }

    if (use_transposed) {
        dim3 grid(NPOINT / 2, B);
        group2_kernel<<<grid, 256, 0, stream>>>(xyz, new_xyz, ft, idx_ws, out);
    } else {
        dim3 grid(NPOINT / 8, B);
        group_kernel<<<grid, 256, 0, stream>>>(xyz, new_xyz, feat, idx_ws, out);
    }
}